// Round 1
// baseline (77916.730 us; speedup 1.0000x reference)
//
#include <hip/hip_runtime.h>
#include <hip/hip_bf16.h>

#define I_DIM 118
#define H_DIM 1024
#define B_DIM 64
#define T_DIM 512
#define FC_DIM 16

// ---------------------------------------------------------------------------
// xT[t][i][b] = x[b][t][i]   (so per-step input reads are coalesced, lane=b)
// ---------------------------------------------------------------------------
__global__ __launch_bounds__(256) void transpose_x(
    const float* __restrict__ x, float* __restrict__ xT)
{
    int idx = blockIdx.x * 256 + threadIdx.x;      // idx = b + 64*(i + I*t)
    int b = idx & 63;
    int rest = idx >> 6;
    int i = rest % I_DIM;
    int t = rest / I_DIM;
    if (t < T_DIM)
        xT[idx] = x[(size_t)b * (T_DIM * I_DIM) + (size_t)t * I_DIM + i];
}

// ---------------------------------------------------------------------------
// 3-row dot product over K=1024 with float4 weight loads (rows 4KB aligned).
// vT is (1024, 64) transposed activations; lane reads vT[k*64+b] (coalesced).
// ---------------------------------------------------------------------------
__device__ inline void dot3_1024(const float* __restrict__ vT, int b,
                                 const float* __restrict__ w0,
                                 const float* __restrict__ w1,
                                 const float* __restrict__ w2,
                                 float& a0, float& a1, float& a2)
{
#pragma unroll 2
    for (int k = 0; k < H_DIM; k += 4) {
        float4 q0 = *(const float4*)(w0 + k);
        float4 q1 = *(const float4*)(w1 + k);
        float4 q2 = *(const float4*)(w2 + k);
        float v0 = vT[(k + 0) * 64 + b];
        float v1 = vT[(k + 1) * 64 + b];
        float v2 = vT[(k + 2) * 64 + b];
        float v3 = vT[(k + 3) * 64 + b];
        a0 = fmaf(v0, q0.x, a0); a1 = fmaf(v0, q1.x, a1); a2 = fmaf(v0, q2.x, a2);
        a0 = fmaf(v1, q0.y, a0); a1 = fmaf(v1, q1.y, a1); a2 = fmaf(v1, q2.y, a2);
        a0 = fmaf(v2, q0.z, a0); a1 = fmaf(v2, q1.z, a1); a2 = fmaf(v2, q2.z, a2);
        a0 = fmaf(v3, q0.w, a0); a1 = fmaf(v3, q1.w, a1); a2 = fmaf(v3, q2.w, a2);
    }
}

// ---------------------------------------------------------------------------
// One GRU cell step.  grid = 256 blocks x 256 thr; thread (b = tid&63,
// jj = tid>>6) computes h_new[b][j], j = blk*4+jj.  All activations in
// transposed (K, B) layout.  hT_prev == nullptr means h_prev = 0.
// kin is 118 (x input) or 1024 (hidden input).
// ---------------------------------------------------------------------------
__global__ __launch_bounds__(256) void gru_step(
    const float* __restrict__ xinT, int kin,
    const float* __restrict__ hT_prev,
    const float* __restrict__ Wih,   // (3H, kin) row-major
    const float* __restrict__ Whh,   // (3H, H) row-major
    const float* __restrict__ bih,
    const float* __restrict__ bhh,
    float* __restrict__ hT_new)      // (H, B)
{
    const int b  = threadIdx.x & 63;
    const int jj = threadIdx.x >> 6;
    const int j  = blockIdx.x * 4 + jj;

    // ---- input-side gates: gi = x @ Wih^T + bih
    float air = bih[j], aiz = bih[j + H_DIM], ain = bih[j + 2 * H_DIM];
    if (kin == H_DIM) {
        dot3_1024(xinT, b,
                  Wih + (size_t)j * H_DIM,
                  Wih + (size_t)(j + H_DIM) * H_DIM,
                  Wih + (size_t)(j + 2 * H_DIM) * H_DIM,
                  air, aiz, ain);
    } else {
        const float* wr = Wih + (size_t)j * kin;
        const float* wz = Wih + (size_t)(j + H_DIM) * kin;
        const float* wn = Wih + (size_t)(j + 2 * H_DIM) * kin;
#pragma unroll 2
        for (int k = 0; k < kin; ++k) {
            float xv = xinT[k * 64 + b];
            air = fmaf(xv, wr[k], air);
            aiz = fmaf(xv, wz[k], aiz);
            ain = fmaf(xv, wn[k], ain);
        }
    }

    // ---- hidden-side gates: gh = h @ Whh^T + bhh
    float ahr = bhh[j], ahz = bhh[j + H_DIM], ahn = bhh[j + 2 * H_DIM];
    float hprev = 0.0f;
    if (hT_prev != nullptr) {
        dot3_1024(hT_prev, b,
                  Whh + (size_t)j * H_DIM,
                  Whh + (size_t)(j + H_DIM) * H_DIM,
                  Whh + (size_t)(j + 2 * H_DIM) * H_DIM,
                  ahr, ahz, ahn);
        hprev = hT_prev[j * 64 + b];
    }

    float r = 1.0f / (1.0f + __expf(-(air + ahr)));
    float z = 1.0f / (1.0f + __expf(-(aiz + ahz)));
    float n = tanhf(ain + r * ahn);
    hT_new[j * 64 + b] = (1.0f - z) * n + z * hprev;
}

// ---------------------------------------------------------------------------
// Head: y = relu(h2 @ fc_W^T + fc_b) @ out_W^T + out_b   -> (64,) fp32
// one block, 1024 threads: thread (b = tid&63, f = tid>>6)
// ---------------------------------------------------------------------------
__global__ __launch_bounds__(1024) void head_kernel(
    const float* __restrict__ h2T,     // (H, B)
    const float* __restrict__ fc_W,    // (16, H)
    const float* __restrict__ fc_b,
    const float* __restrict__ out_W,   // (1, 16)
    const float* __restrict__ out_b,
    float* __restrict__ y)
{
    __shared__ float acc_s[FC_DIM][B_DIM];
    const int b = threadIdx.x & 63;
    const int f = threadIdx.x >> 6;
    const float* w = fc_W + (size_t)f * H_DIM;
    float a = fc_b[f];
#pragma unroll 4
    for (int k = 0; k < H_DIM; ++k)
        a = fmaf(h2T[k * 64 + b], w[k], a);
    a = fmaxf(a, 0.0f);
    acc_s[f][b] = a * out_W[f];
    __syncthreads();
    if (threadIdx.x < 64) {
        float s = out_b[0];
#pragma unroll
        for (int f2 = 0; f2 < FC_DIM; ++f2) s += acc_s[f2][b];
        y[b] = s;
    }
}

// ---------------------------------------------------------------------------
extern "C" void kernel_launch(void* const* d_in, const int* in_sizes, int n_in,
                              void* d_out, int out_size, void* d_ws, size_t ws_size,
                              hipStream_t stream)
{
    const float* x      = (const float*)d_in[0];
    const float* e_Wih0 = (const float*)d_in[1];
    const float* e_Whh0 = (const float*)d_in[2];
    const float* e_bih0 = (const float*)d_in[3];
    const float* e_bhh0 = (const float*)d_in[4];
    const float* e_Wih1 = (const float*)d_in[5];
    const float* e_Whh1 = (const float*)d_in[6];
    const float* e_bih1 = (const float*)d_in[7];
    const float* e_bhh1 = (const float*)d_in[8];
    const float* d_Wih0 = (const float*)d_in[9];
    const float* d_Whh0 = (const float*)d_in[10];
    const float* d_bih0 = (const float*)d_in[11];
    const float* d_bhh0 = (const float*)d_in[12];
    const float* d_Wih1 = (const float*)d_in[13];
    const float* d_Whh1 = (const float*)d_in[14];
    const float* d_bih1 = (const float*)d_in[15];
    const float* d_bhh1 = (const float*)d_in[16];
    const float* fc_W   = (const float*)d_in[17];
    const float* fc_b   = (const float*)d_in[18];
    const float* out_W  = (const float*)d_in[19];
    const float* out_b  = (const float*)d_in[20];

    // workspace layout (fp32)
    char* ws = (char*)d_ws;
    const size_t HB = (size_t)H_DIM * B_DIM;                  // 65536 floats
    float* xT     = (float*)ws;                               // T*I*B
    ws += (size_t)T_DIM * I_DIM * B_DIM * sizeof(float);
    float* h1_all = (float*)ws;                               // T*H*B
    ws += (size_t)T_DIM * HB * sizeof(float);
    float* h2a    = (float*)ws;  ws += HB * sizeof(float);
    float* h2b    = (float*)ws;  ws += HB * sizeof(float);
    float* hd1    = (float*)ws;  ws += HB * sizeof(float);
    float* hd2    = (float*)ws;  ws += HB * sizeof(float);
    (void)ws_size; (void)n_in; (void)in_sizes; (void)out_size;

    // 1) transpose x  -> xT (T, I, B)
    {
        int total = T_DIM * I_DIM * B_DIM;
        transpose_x<<<(total + 255) / 256, 256, 0, stream>>>(x, xT);
    }

    // 2) encoder layer 1: 512 sequential steps, store every h1[t]
    for (int t = 0; t < T_DIM; ++t) {
        const float* xin = xT + (size_t)t * I_DIM * B_DIM;
        const float* hp  = (t == 0) ? nullptr : (h1_all + (size_t)(t - 1) * HB);
        gru_step<<<256, 256, 0, stream>>>(xin, I_DIM, hp,
                                          e_Wih0, e_Whh0, e_bih0, e_bhh0,
                                          h1_all + (size_t)t * HB);
    }

    // 3) encoder layer 2: 512 sequential steps, ping-pong h2
    for (int t = 0; t < T_DIM; ++t) {
        const float* xin = h1_all + (size_t)t * HB;
        const float* hp  = (t == 0) ? nullptr : ((t & 1) ? h2b : h2a);
        float* hn        = (t & 1) ? h2a : h2b;   // t=0 writes h2b, t=511 writes h2a
        gru_step<<<256, 256, 0, stream>>>(xin, H_DIM, hp,
                                          e_Wih1, e_Whh1, e_bih1, e_bhh1, hn);
    }
    const float* h2_enc = h2a;   // t=511 (odd) wrote h2a

    // 4) decoder cell 1: input = x[:, T-1, :], h = h1[T-1]
    gru_step<<<256, 256, 0, stream>>>(xT + (size_t)(T_DIM - 1) * I_DIM * B_DIM,
                                      I_DIM, h1_all + (size_t)(T_DIM - 1) * HB,
                                      d_Wih0, d_Whh0, d_bih0, d_bhh0, hd1);

    // 5) decoder cell 2: input = hd1, h = h2_enc
    gru_step<<<256, 256, 0, stream>>>(hd1, H_DIM, h2_enc,
                                      d_Wih1, d_Whh1, d_bih1, d_bhh1, hd2);

    // 6) FC head
    head_kernel<<<1, 1024, 0, stream>>>(hd2, fc_W, fc_b, out_W, out_b,
                                        (float*)d_out);
}

// Round 2
// 40298.502 us; speedup vs baseline: 1.9335x; 1.9335x over previous
//
#include <hip/hip_runtime.h>
#include <hip/hip_bf16.h>

// ---------------------------------------------------------------------------
// NetGRU on MI355X, round 2.
// Design: layer-split GRU passes. Each pass = ONE persistent kernel,
// 256 blocks x 64 threads (1 wave), block (bm,bn) owns output tile
// (16 batch rows m0..m0+15) x (16 hidden cols j0..j0+15) and its 3 gate rows
// -> GRU combine is entirely block-local. Steps separated by a 2-level
// device-scope atomic barrier (8 group counters + 1 global).
// Matvecs via v_mfma_f32_16x16x32_bf16: A = activations [b][k] row-major bf16,
// B = weight rows [j][k] row-major bf16 (B-operand = W^T per fragment layout),
// fp32 accumulation; h master kept in fp32 for the z*h term.
// ---------------------------------------------------------------------------

#define I_ORIG 118
#define I_PAD  128
#define H_DIM  1024
#define B_DIM  64
#define T_DIM  512
#define FC_DIM 16
#define HB     (B_DIM * H_DIM)     // 65536 elements per h slot

typedef __hip_bfloat16 bf16;
typedef __attribute__((ext_vector_type(8))) short short8v;   // 8 bf16 = 4 VGPR
typedef __attribute__((ext_vector_type(4))) float f32x4;

__device__ __forceinline__ short8v ldg8(const bf16* p) {
    return *reinterpret_cast<const short8v*>(p);
}

// ---------------------------------------------------------------------------
// x[b][t][i] (f32) -> x_bf[t][b][c] (bf16, c padded 118->128 with zeros)
// ---------------------------------------------------------------------------
__global__ __launch_bounds__(256) void cvt_x_kernel(
    const float* __restrict__ x, bf16* __restrict__ out)
{
    int idx  = blockIdx.x * 256 + threadIdx.x;   // c + 128*(b + 64*t), exact
    int c    = idx & 127;
    int rest = idx >> 7;
    int b    = rest & 63;
    int t    = rest >> 6;
    float v  = (c < I_ORIG) ? x[((long)b * T_DIM + t) * I_ORIG + c] : 0.0f;
    out[idx] = __float2bfloat16(v);
}

// ---------------------------------------------------------------------------
// f32 weight (rows x kin) -> bf16 (rows x kp), zero-padded columns
// ---------------------------------------------------------------------------
__global__ __launch_bounds__(256) void cvt_pad(
    const float* __restrict__ in, bf16* __restrict__ out,
    int kin, int kp, long total)
{
    long idx = (long)blockIdx.x * 256 + threadIdx.x;
    if (idx >= total) return;
    int  c = (int)(idx % kp);
    long r = idx / kp;
    out[idx] = __float2bfloat16(c < kin ? in[r * kin + c] : 0.0f);
}

// ---------------------------------------------------------------------------
// Persistent GRU pass kernel.
//   grid 256 x 64.  bn = 8*(bid&7) + ((bid>>3)&7)  (XCD-aware: XCD x serves
//   j-tiles 8x..8x+7 for all 4 bm -> per-XCD weight slice ~1.5MB, L2-resident)
//   bm = bid>>6.
// Per step: hidden-side matvec (K=1024, Wh) + input-side matvec (K=Kx, Wx),
// 3 gates each via MFMA; GRU combine; 2-level barrier (skipped on last step).
// Slot arithmetic: in_slot=(t0in+t)%mod_in, out_slot=(t0out+t)%mod_out.
// ---------------------------------------------------------------------------
__global__ __launch_bounds__(64) void gru_pass(
    const bf16* __restrict__ xbase, long xstride, int Kx,
    const bf16* __restrict__ Wx,          // [3H][Kx] bf16
    const bf16* __restrict__ Wh,          // [3H][H]  bf16
    const float* __restrict__ bihv, const float* __restrict__ bhhv,
    const bf16* __restrict__ hin_base, int t0in, int mod_in,
    bf16* __restrict__ hout_base, int t0out, int mod_out,
    const float* hprev_f32, float* hnew_f32,      // may alias (no restrict!)
    int nsteps, unsigned* cnt)
{
    const int lane = threadIdx.x;
    const int ln   = lane & 15;           // j-offset (B/C col), A row offset
    const int lk   = lane >> 4;           // k-group
    const int bid  = blockIdx.x;
    const int bn   = ((bid & 7) << 3) | ((bid >> 3) & 7);
    const int bm   = bid >> 6;
    const int j    = bn * 16 + ln;
    const int m0   = bm * 16;

    // per-lane weight row pointers (gate rows j, j+H, j+2H)
    const bf16* whr = Wh + (long)j * H_DIM + lk * 8;
    const bf16* whz = whr + (long)H_DIM * H_DIM;
    const bf16* whn = whz + (long)H_DIM * H_DIM;
    const bf16* wxr = Wx + (long)j * Kx + lk * 8;
    const bf16* wxz = wxr + (long)H_DIM * Kx;
    const bf16* wxn = wxz + (long)H_DIM * Kx;

    const float b_r  = bihv[j] + bhhv[j];
    const float b_z  = bihv[j + H_DIM] + bhhv[j + H_DIM];
    const float b_ni = bihv[j + 2 * H_DIM];
    const float b_nh = bhhv[j + 2 * H_DIM];

    const long arow     = (long)(m0 + ln);
    const int  ksteps_x = Kx >> 5;

    for (int t = 0; t < nsteps; ++t) {
        const bf16* ha = hin_base + (long)((t0in + t) % mod_in) * HB
                         + arow * H_DIM + lk * 8;
        const bf16* xa = xbase + (long)t * xstride + arow * Kx + lk * 8;

        f32x4 ar  = {b_r,  b_r,  b_r,  b_r };
        f32x4 az  = {b_z,  b_z,  b_z,  b_z };
        f32x4 ani = {b_ni, b_ni, b_ni, b_ni};
        f32x4 anh = {b_nh, b_nh, b_nh, b_nh};

        // hidden side: gh = h_prev @ Wh^T  (K = 1024)
#pragma unroll 4
        for (int ks = 0; ks < 32; ++ks) {
            short8v a   = ldg8(ha  + ks * 32);
            short8v br  = ldg8(whr + ks * 32);
            short8v bz  = ldg8(whz + ks * 32);
            short8v bnn = ldg8(whn + ks * 32);
            ar  = __builtin_amdgcn_mfma_f32_16x16x32_bf16(a, br,  ar,  0, 0, 0);
            az  = __builtin_amdgcn_mfma_f32_16x16x32_bf16(a, bz,  az,  0, 0, 0);
            anh = __builtin_amdgcn_mfma_f32_16x16x32_bf16(a, bnn, anh, 0, 0, 0);
        }
        // input side: gi = x @ Wx^T  (K = Kx)
#pragma unroll 4
        for (int ks = 0; ks < ksteps_x; ++ks) {
            short8v a   = ldg8(xa  + ks * 32);
            short8v br  = ldg8(wxr + ks * 32);
            short8v bz  = ldg8(wxz + ks * 32);
            short8v bnn = ldg8(wxn + ks * 32);
            ar  = __builtin_amdgcn_mfma_f32_16x16x32_bf16(a, br,  ar,  0, 0, 0);
            az  = __builtin_amdgcn_mfma_f32_16x16x32_bf16(a, bz,  az,  0, 0, 0);
            ani = __builtin_amdgcn_mfma_f32_16x16x32_bf16(a, bnn, ani, 0, 0, 0);
        }

        // combine: C/D layout col = lane&15 (j), row = 4*(lane>>4)+e (b)
        bf16* ho = hout_base + (long)((t0out + t) % mod_out) * HB;
#pragma unroll
        for (int e = 0; e < 4; ++e) {
            int  brow = m0 + lk * 4 + e;
            long o    = brow * (long)H_DIM + j;
            float r  = 1.0f / (1.0f + __expf(-ar[e]));
            float z  = 1.0f / (1.0f + __expf(-az[e]));
            float n  = tanhf(ani[e] + r * anh[e]);
            float hv = (1.0f - z) * n + z * hprev_f32[o];
            hnew_f32[o] = hv;
            ho[o] = __float2bfloat16(hv);
        }

        // inter-step barrier (2-level, device scope); skip after final step
        if (t != nsteps - 1) {
            if (lane == 0) {
                __threadfence();
                unsigned old = __hip_atomic_fetch_add(
                    &cnt[1 + (bid & 7)], 1u,
                    __ATOMIC_ACQ_REL, __HIP_MEMORY_SCOPE_AGENT);
                if (old == 32u * (unsigned)(t + 1) - 1u)
                    __hip_atomic_fetch_add(
                        &cnt[0], 1u,
                        __ATOMIC_ACQ_REL, __HIP_MEMORY_SCOPE_AGENT);
                while (__hip_atomic_load(&cnt[0], __ATOMIC_ACQUIRE,
                                         __HIP_MEMORY_SCOPE_AGENT)
                       < 8u * (unsigned)(t + 1))
                    __builtin_amdgcn_s_sleep(2);
                __threadfence();
            }
            __syncthreads();
        }
    }
}

// ---------------------------------------------------------------------------
// Head: y = relu(h2 @ fc_W^T + fc_b) @ out_W^T + out_b, h2 row-major [64][1024]
// ---------------------------------------------------------------------------
__global__ __launch_bounds__(1024) void head_kernel(
    const float* __restrict__ h2,
    const float* __restrict__ fc_W, const float* __restrict__ fc_b,
    const float* __restrict__ out_W, const float* __restrict__ out_b,
    float* __restrict__ y)
{
    __shared__ float acc_s[FC_DIM][B_DIM];
    const int b = threadIdx.x & 63;
    const int f = threadIdx.x >> 6;
    const float* w = fc_W + (long)f * H_DIM;
    const float* h = h2 + (long)b * H_DIM;
    float a = fc_b[f];
#pragma unroll 8
    for (int k = 0; k < H_DIM; ++k)
        a = fmaf(h[k], w[k], a);
    a = fmaxf(a, 0.0f);
    acc_s[f][b] = a * out_W[f];
    __syncthreads();
    if (threadIdx.x < 64) {
        float s = out_b[0];
#pragma unroll
        for (int f2 = 0; f2 < FC_DIM; ++f2) s += acc_s[f2][b];
        y[b] = s;
    }
}

// ---------------------------------------------------------------------------
extern "C" void kernel_launch(void* const* d_in, const int* in_sizes, int n_in,
                              void* d_out, int out_size, void* d_ws, size_t ws_size,
                              hipStream_t stream)
{
    const float* x      = (const float*)d_in[0];
    const float* e_Wih0 = (const float*)d_in[1];
    const float* e_Whh0 = (const float*)d_in[2];
    const float* e_bih0 = (const float*)d_in[3];
    const float* e_bhh0 = (const float*)d_in[4];
    const float* e_Wih1 = (const float*)d_in[5];
    const float* e_Whh1 = (const float*)d_in[6];
    const float* e_bih1 = (const float*)d_in[7];
    const float* e_bhh1 = (const float*)d_in[8];
    const float* d_Wih0 = (const float*)d_in[9];
    const float* d_Whh0 = (const float*)d_in[10];
    const float* d_bih0 = (const float*)d_in[11];
    const float* d_bhh0 = (const float*)d_in[12];
    const float* d_Wih1 = (const float*)d_in[13];
    const float* d_Whh1 = (const float*)d_in[14];
    const float* d_bih1 = (const float*)d_in[15];
    const float* d_bhh1 = (const float*)d_in[16];
    const float* fc_W   = (const float*)d_in[17];
    const float* fc_b   = (const float*)d_in[18];
    const float* out_W  = (const float*)d_in[19];
    const float* out_b  = (const float*)d_in[20];
    (void)in_sizes; (void)n_in; (void)out_size; (void)ws_size;

    // ---- workspace carve-up (~112 MB; round-1 proved >=150MB available)
    char* p = (char*)d_ws;
    auto alloc = [&](size_t bytes) -> char* {
        char* r = p; p += (bytes + 255) & ~(size_t)255; return r;
    };
    bf16*  x_bf  = (bf16*)alloc((size_t)T_DIM * B_DIM * I_PAD * 2);  // [t][b][128]
    bf16*  wih0e = (bf16*)alloc(3072ull * 128 * 2);
    bf16*  whh0e = (bf16*)alloc(3072ull * 1024 * 2);
    bf16*  wih1e = (bf16*)alloc(3072ull * 1024 * 2);
    bf16*  whh1e = (bf16*)alloc(3072ull * 1024 * 2);
    bf16*  wih0d = (bf16*)alloc(3072ull * 128 * 2);
    bf16*  whh0d = (bf16*)alloc(3072ull * 1024 * 2);
    bf16*  wih1d = (bf16*)alloc(3072ull * 1024 * 2);
    bf16*  whh1d = (bf16*)alloc(3072ull * 1024 * 2);
    bf16*  h1all = (bf16*)alloc(513ull * HB * 2);   // slots 0..512, slot s = h1 after s steps
    bf16*  h2buf = (bf16*)alloc(2ull * HB * 2);     // ping-pong
    bf16*  hd1b  = (bf16*)alloc((size_t)HB * 2);
    bf16*  hd2b  = (bf16*)alloc((size_t)HB * 2);
    float* hf1   = (float*)alloc((size_t)HB * 4);   // layer-1 fp32 master
    float* hf2   = (float*)alloc((size_t)HB * 4);   // layer-2 fp32 master
    float* hd1f  = (float*)alloc((size_t)HB * 4);
    float* hd2f  = (float*)alloc((size_t)HB * 4);
    unsigned* cnt1 = (unsigned*)alloc(64);
    unsigned* cnt2 = (unsigned*)alloc(64);

    // ---- prep: converts + zero-init
    cvt_x_kernel<<<(T_DIM * B_DIM * I_PAD) / 256, 256, 0, stream>>>(x, x_bf);
    auto cvt = [&](const float* in, bf16* out, int kin, int kp) {
        long total = 3072L * kp;
        cvt_pad<<<(int)((total + 255) / 256), 256, 0, stream>>>(in, out, kin, kp, total);
    };
    cvt(e_Wih0, wih0e, 118, 128);
    cvt(e_Whh0, whh0e, 1024, 1024);
    cvt(e_Wih1, wih1e, 1024, 1024);
    cvt(e_Whh1, whh1e, 1024, 1024);
    cvt(d_Wih0, wih0d, 118, 128);
    cvt(d_Whh0, whh0d, 1024, 1024);
    cvt(d_Wih1, wih1d, 1024, 1024);
    cvt(d_Whh1, whh1d, 1024, 1024);

    hipMemsetAsync(h1all, 0, (size_t)HB * 2, stream);   // h1 slot 0 = zeros
    hipMemsetAsync(h2buf, 0, (size_t)HB * 2, stream);   // h2 slot 0 = zeros
    hipMemsetAsync(hf1,   0, (size_t)HB * 4, stream);
    hipMemsetAsync(hf2,   0, (size_t)HB * 4, stream);
    hipMemsetAsync(cnt1,  0, 64, stream);
    hipMemsetAsync(cnt2,  0, 64, stream);

    // ---- encoder layer 1: 512 persistent steps; h1[t] -> slot t+1
    gru_pass<<<256, 64, 0, stream>>>(
        x_bf, (long)B_DIM * I_PAD, I_PAD, wih0e, whh0e, e_bih0, e_bhh0,
        h1all, 0, 1024, h1all, 1, 1024, hf1, hf1, T_DIM, cnt1);

    // ---- encoder layer 2: 512 persistent steps; input = h1[t] (slot t+1)
    gru_pass<<<256, 64, 0, stream>>>(
        h1all + (long)HB, (long)HB, H_DIM, wih1e, whh1e, e_bih1, e_bhh1,
        h2buf, 0, 2, h2buf, 1, 2, hf2, hf2, T_DIM, cnt2);
    // final h2 lands in slot (1+511)%2 = 0

    // ---- decoder cell 1: x = x[:,511,:], h = h1[511] (slot 512)
    gru_pass<<<256, 64, 0, stream>>>(
        x_bf + 511L * B_DIM * I_PAD, 0, I_PAD, wih0d, whh0d, d_bih0, d_bhh0,
        h1all, 512, 1024, hd1b, 0, 1, hf1, hd1f, 1, nullptr);

    // ---- decoder cell 2: x = hd1, h = h2 (slot 0)
    gru_pass<<<256, 64, 0, stream>>>(
        hd1b, 0, H_DIM, wih1d, whh1d, d_bih1, d_bhh1,
        h2buf, 0, 1, hd2b, 0, 1, hf2, hd2f, 1, nullptr);

    // ---- FC head
    head_kernel<<<1, 1024, 0, stream>>>(hd2f, fc_W, fc_b, out_W, out_b,
                                        (float*)d_out);
}

// Round 3
// 5217.239 us; speedup vs baseline: 14.9345x; 7.7241x over previous
//
#include <hip/hip_runtime.h>
#include <hip/hip_bf16.h>

#define H_DIM 1024
#define B_DIM 64
#define T_DIM 512
#define I_PAD 128
#define I_ORIG 118
#define FC_DIM 16
#define HB (B_DIM * H_DIM)

typedef __hip_bfloat16 bf16;
typedef __attribute__((ext_vector_type(8))) short short8v;
typedef __attribute__((ext_vector_type(4))) float f32x4;

#define MFMA16(a, b, c) __builtin_amdgcn_mfma_f32_16x16x32_bf16(a, b, c, 0, 0, 0)

__device__ __forceinline__ short8v ldg8(const bf16* p) {
    return *reinterpret_cast<const short8v*>(p);
}
// 16B load that bypasses L2 (coherent at IF$): two relaxed agent-scope 8B atomic loads
__device__ __forceinline__ short8v ld_byp16(const bf16* p) {
    union { unsigned long long u[2]; short8v v; } r;
    const unsigned long long* q = reinterpret_cast<const unsigned long long*>(p);
    r.u[0] = __hip_atomic_load(q,     __ATOMIC_RELAXED, __HIP_MEMORY_SCOPE_AGENT);
    r.u[1] = __hip_atomic_load(q + 1, __ATOMIC_RELAXED, __HIP_MEMORY_SCOPE_AGENT);
    return r.v;
}
__device__ __forceinline__ unsigned short f2bf_bits(float f) {
    union { bf16 h; unsigned short s; } u;
    u.h = __float2bfloat16(f);
    return u.s;
}

// ---------------------------------------------------------------------------
// x[b][t][i] f32 -> x_bf[t][b][c] bf16 (c padded 118->128 with zeros)
// ---------------------------------------------------------------------------
__global__ __launch_bounds__(256) void cvt_x_kernel(
    const float* __restrict__ x, bf16* __restrict__ out)
{
    int idx  = blockIdx.x * 256 + threadIdx.x;
    int c    = idx & 127;
    int rest = idx >> 7;
    int b    = rest & 63;
    int t    = rest >> 6;
    float v  = (c < I_ORIG) ? x[((long)b * T_DIM + t) * I_ORIG + c] : 0.0f;
    out[idx] = __float2bfloat16(v);
}

// f32 weight (rows x kin) -> bf16 (rows x kp), zero-padded columns
__global__ __launch_bounds__(256) void cvt_pad(
    const float* __restrict__ in, bf16* __restrict__ out,
    int kin, int kp, long total)
{
    long idx = (long)blockIdx.x * 256 + threadIdx.x;
    if (idx >= total) return;
    int  c = (int)(idx % kp);
    long r = idx / kp;
    out[idx] = __float2bfloat16(c < kin ? in[r * kin + c] : 0.0f);
}

// ---------------------------------------------------------------------------
// Persistent GRU pass. grid 256 x 256 (4 waves).
// Block bid: bn = bid&63 (j-tile of 16), grp = bid>>6 (batch tile of 16 rows).
// Groups are fully independent (disjoint batch rows): per-group barrier of 64.
// Wave w handles K-slice [w*256, w*256+256) of the hidden matvec (and the
// input matvec); partials reduced via LDS. Whh (and Wx if WXK==128) live in
// LDS, XOR-swizzled. Recurrent h exchanged via L2-bypass (sc1) relaxed
// atomics; no cache invalidates anywhere in the loop.
// SEQ: bf16 h slots = hbfA + t*HB (in), hbfB + t*HB (out)  [pass 1: h1_all]
// !SEQ: ping-pong between hbfA/hbfB.  f32 master always ping-pongs hfA/hfB.
// ---------------------------------------------------------------------------
template<int WXK, bool WXG, bool SEQ>
__global__ __launch_bounds__(256, 1) void gru_pass(
    const bf16* __restrict__ xbase, long xstride,
    const bf16* __restrict__ WxG,   // [3*1024][WXK] bf16 (staged to LDS if !WXG)
    const bf16* __restrict__ WhG,   // [3*1024][1024] bf16
    const float* __restrict__ bih, const float* __restrict__ bhh,
    bf16* hbfA, bf16* hbfB,
    float* hfA_, float* hfB_,
    int nsteps, unsigned* cnt)
{
    extern __shared__ char smem[];
    constexpr int WH_BYTES = 3 * 16 * 1024 * 2;                  // 98304
    constexpr int WX_BYTES = WXG ? 0 : 3 * 16 * WXK * 2;
    float* sm_red = (float*)(smem + WH_BYTES + WX_BYTES);        // [4][4][16][16]

    const int tid  = threadIdx.x;
    const int w    = tid >> 6;
    const int lane = tid & 63;
    const int ln   = lane & 15;
    const int lk   = lane >> 4;
    const int bid  = blockIdx.x;
    const int bn   = bid & 63;
    const int grp  = bid >> 6;
    const int j0   = bn * 16;
    const int m0   = grp * 16;
    const int j    = j0 + ln;

    // ---- stage Whh into LDS (swizzled): rows (g,jj), 2048B each
    for (int c = tid; c < WH_BYTES / 16; c += 256) {
        int lin = c * 16;
        int row = lin >> 11;               // g*16 + jj
        int wb  = lin & 2047;
        int g   = row >> 4, jj = row & 15;
        const bf16* src = WhG + ((long)(g * 1024 + j0 + jj) << 10) + (wb >> 1);
        *reinterpret_cast<short8v*>(smem + (lin ^ ((jj & 7) << 4))) = ldg8(src);
    }
    if constexpr (!WXG) {
        for (int c = tid; c < WX_BYTES / 16; c += 256) {
            int lin = c * 16;
            int row = lin / (WXK * 2);
            int wb  = lin % (WXK * 2);
            int g   = row >> 4, jj = row & 15;
            const bf16* src = WxG + (long)(g * 1024 + j0 + jj) * WXK + (wb >> 1);
            *reinterpret_cast<short8v*>(smem + WH_BYTES + (lin ^ ((jj & 7) << 4))) = ldg8(src);
        }
    }
    __syncthreads();

    const int wkoh = w << 8;                                   // hidden K offset
    const int wkox = (WXK == 128) ? (w << 5) : (w << 8);       // input K offset
    const int swz  = (ln & 7) << 4;
    const int whb0 = ln * 2048 + ((wkoh + lk * 8) << 1);

    const float bias_r  = bih[j] + bhh[j];
    const float bias_z  = bih[j + H_DIM] + bhh[j + H_DIM];
    const float bias_ni = bih[j + 2 * H_DIM];
    const float bias_nh = bhh[j + 2 * H_DIM];

    // combine-role: this lane produces element (row gm, col j)
    const int crow = (w << 2) | lk;
    const int gm   = m0 + crow;
    const int jp   = j & ~1;
    const int wrd  = ((w ^ (ln & 3)) << 2) | lk;

    constexpr int NKX = (WXK == 128) ? 1 : 8;
    short8v xcur[NKX];
    {
        const bf16* xr = xbase + (long)(m0 + ln) * WXK + wkox + lk * 8;
#pragma unroll
        for (int ks = 0; ks < NKX; ++ks) xcur[ks] = ldg8(xr + ks * 32);
    }

    for (int t = 0; t < nsteps; ++t) {
        const bf16* bf_in  = SEQ ? hbfA + (long)t * HB : ((t & 1) ? hbfB : hbfA);
        bf16*       bf_out = SEQ ? hbfB + (long)t * HB : ((t & 1) ? hbfA : hbfB);
        const float* f_in  = (t & 1) ? hfB_ : hfA_;
        float*       f_out = (t & 1) ? hfA_ : hfB_;

        // early: f32 h_prev for the z*h term (bypass) + hidden A fragments
        float hprev = __hip_atomic_load(f_in + (long)gm * H_DIM + j,
                                        __ATOMIC_RELAXED, __HIP_MEMORY_SCOPE_AGENT);
        const bf16* ha = bf_in + (long)(m0 + ln) * H_DIM + wkoh + lk * 8;
        short8v ah[8];
#pragma unroll
        for (int ks = 0; ks < 8; ++ks) ah[ks] = ld_byp16(ha + ks * 32);

        f32x4 aR{0,0,0,0}, aZ{0,0,0,0}, aNI{0,0,0,0}, aNH{0,0,0,0};

        // hidden side (Whh from LDS)
#pragma unroll
        for (int ks = 0; ks < 8; ++ks) {
            int o = whb0 + ks * 64;
            short8v br  = *(const short8v*)(smem + ((o        ) ^ swz));
            short8v bz  = *(const short8v*)(smem + ((o + 32768) ^ swz));
            short8v bnn = *(const short8v*)(smem + ((o + 65536) ^ swz));
            aR  = MFMA16(ah[ks], br,  aR);
            aZ  = MFMA16(ah[ks], bz,  aZ);
            aNH = MFMA16(ah[ks], bnn, aNH);
        }
        // input side
        if constexpr (WXK == 128) {
            int o = WH_BYTES + ln * 256 + ((wkox + lk * 8) << 1);
            short8v br  = *(const short8v*)(smem + ((o       ) ^ swz));
            short8v bz  = *(const short8v*)(smem + ((o + 4096) ^ swz));
            short8v bnn = *(const short8v*)(smem + ((o + 8192) ^ swz));
            aR  = MFMA16(xcur[0], br,  aR);
            aZ  = MFMA16(xcur[0], bz,  aZ);
            aNI = MFMA16(xcur[0], bnn, aNI);
        } else {
            const bf16* wxr = WxG + (long)(j0 + ln) * 1024 + wkox + lk * 8;
#pragma unroll
            for (int ks = 0; ks < 8; ++ks) {
                short8v br  = ldg8(wxr + ks * 32);
                short8v bz  = ldg8(wxr + (1 << 20) + ks * 32);
                short8v bnn = ldg8(wxr + (2 << 20) + ks * 32);
                aR  = MFMA16(xcur[ks], br,  aR);
                aZ  = MFMA16(xcur[ks], bz,  aZ);
                aNI = MFMA16(xcur[ks], bnn, aNI);
            }
        }
        // prefetch next step's input A (independent of the barrier)
        if (t + 1 < nsteps) {
            const bf16* xr = xbase + (long)(t + 1) * xstride
                             + (long)(m0 + ln) * WXK + wkox + lk * 8;
#pragma unroll
            for (int ks = 0; ks < NKX; ++ks) xcur[ks] = ldg8(xr + ks * 32);
        }

        // write partials: red[w][a][ln][4*(lk^(ln&3)) + e]
        {
            int wd0 = (lk ^ (ln & 3)) << 2;
#pragma unroll
            for (int a = 0; a < 4; ++a) {
                f32x4 v = (a == 0) ? aR : (a == 1) ? aZ : (a == 2) ? aNI : aNH;
                *(f32x4*)(sm_red + ((((w << 2) + a) * 16 + ln) << 4) + wd0) = v;
            }
        }
        __syncthreads();

        // reduce across waves + combine (one element per lane)
        float sR = 0, sZ = 0, sNI = 0, sNH = 0;
#pragma unroll
        for (int w2 = 0; w2 < 4; ++w2) {
            const float* rp = sm_red + (((w2 << 2) * 16 + ln) << 4) + wrd;
            sR  += rp[0];
            sZ  += rp[256];
            sNI += rp[512];
            sNH += rp[768];
        }
        float rr = 1.0f / (1.0f + __expf(-(sR + bias_r)));
        float zz = 1.0f / (1.0f + __expf(-(sZ + bias_z)));
        float xn = (sNI + bias_ni) + rr * (sNH + bias_nh);
        float nn = 2.0f / (1.0f + __expf(-2.0f * xn)) - 1.0f;
        float hv = (1.0f - zz) * nn + zz * hprev;

        float ho = __shfl_xor(hv, 1);
        if ((ln & 1) == 0) {
            unsigned pk = (unsigned)f2bf_bits(hv) | ((unsigned)f2bf_bits(ho) << 16);
            __hip_atomic_store((unsigned*)(bf_out + (long)gm * H_DIM + jp), pk,
                               __ATOMIC_RELAXED, __HIP_MEMORY_SCOPE_AGENT);
        } else {
            union { float f[2]; unsigned long long u; } pv;
            pv.f[0] = ho; pv.f[1] = hv;
            __hip_atomic_store((unsigned long long*)(f_out + (long)gm * H_DIM + jp),
                               pv.u, __ATOMIC_RELAXED, __HIP_MEMORY_SCOPE_AGENT);
        }

        // per-group barrier: relaxed atomics only, no cache maintenance
        if (t != nsteps - 1) {
            asm volatile("s_waitcnt vmcnt(0)" ::: "memory");
            __syncthreads();
            if (tid == 0) {
                unsigned* c = cnt + (grp << 6);   // 256B apart
                __hip_atomic_fetch_add(c, 1u, __ATOMIC_RELAXED,
                                       __HIP_MEMORY_SCOPE_AGENT);
                unsigned tgt = 64u * (unsigned)(t + 1);
                while (__hip_atomic_load(c, __ATOMIC_RELAXED,
                                         __HIP_MEMORY_SCOPE_AGENT) < tgt)
                    __builtin_amdgcn_s_sleep(1);
            }
            __syncthreads();
        }
    }
}

// ---------------------------------------------------------------------------
// Head: y = relu(h2 @ fc_W^T + fc_b) @ out_W^T + out_b, h2 f32 [64][1024]
// ---------------------------------------------------------------------------
__global__ __launch_bounds__(1024) void head_kernel(
    const float* __restrict__ h2,
    const float* __restrict__ fc_W, const float* __restrict__ fc_b,
    const float* __restrict__ out_W, const float* __restrict__ out_b,
    float* __restrict__ y)
{
    __shared__ float acc_s[FC_DIM][B_DIM];
    const int b = threadIdx.x & 63;
    const int f = threadIdx.x >> 6;
    const float* wp = fc_W + (long)f * H_DIM;
    const float* hp = h2 + (long)b * H_DIM;
    float a = fc_b[f];
#pragma unroll 8
    for (int k = 0; k < H_DIM; ++k)
        a = fmaf(hp[k], wp[k], a);
    a = fmaxf(a, 0.0f);
    acc_s[f][b] = a * out_W[f];
    __syncthreads();
    if (threadIdx.x < 64) {
        float s = out_b[0];
#pragma unroll
        for (int f2 = 0; f2 < FC_DIM; ++f2) s += acc_s[f2][b];
        y[b] = s;
    }
}

// ---------------------------------------------------------------------------
extern "C" void kernel_launch(void* const* d_in, const int* in_sizes, int n_in,
                              void* d_out, int out_size, void* d_ws, size_t ws_size,
                              hipStream_t stream)
{
    const float* x      = (const float*)d_in[0];
    const float* e_Wih0 = (const float*)d_in[1];
    const float* e_Whh0 = (const float*)d_in[2];
    const float* e_bih0 = (const float*)d_in[3];
    const float* e_bhh0 = (const float*)d_in[4];
    const float* e_Wih1 = (const float*)d_in[5];
    const float* e_Whh1 = (const float*)d_in[6];
    const float* e_bih1 = (const float*)d_in[7];
    const float* e_bhh1 = (const float*)d_in[8];
    const float* d_Wih0 = (const float*)d_in[9];
    const float* d_Whh0 = (const float*)d_in[10];
    const float* d_bih0 = (const float*)d_in[11];
    const float* d_bhh0 = (const float*)d_in[12];
    const float* d_Wih1 = (const float*)d_in[13];
    const float* d_Whh1 = (const float*)d_in[14];
    const float* d_bih1 = (const float*)d_in[15];
    const float* d_bhh1 = (const float*)d_in[16];
    const float* fc_W   = (const float*)d_in[17];
    const float* fc_b   = (const float*)d_in[18];
    const float* out_W  = (const float*)d_in[19];
    const float* out_b  = (const float*)d_in[20];
    (void)in_sizes; (void)n_in; (void)out_size; (void)ws_size;

    char* p = (char*)d_ws;
    auto alloc = [&](size_t bytes) -> char* {
        char* r = p; p += (bytes + 255) & ~(size_t)255; return r;
    };
    bf16*  x_bf  = (bf16*)alloc((size_t)T_DIM * B_DIM * I_PAD * 2);
    bf16*  wih0e = (bf16*)alloc(3072ull * 128 * 2);
    bf16*  whh0e = (bf16*)alloc(3072ull * 1024 * 2);
    bf16*  wih1e = (bf16*)alloc(3072ull * 1024 * 2);
    bf16*  whh1e = (bf16*)alloc(3072ull * 1024 * 2);
    bf16*  wih0d = (bf16*)alloc(3072ull * 128 * 2);
    bf16*  whh0d = (bf16*)alloc(3072ull * 1024 * 2);
    bf16*  wih1d = (bf16*)alloc(3072ull * 1024 * 2);
    bf16*  whh1d = (bf16*)alloc(3072ull * 1024 * 2);
    bf16*  h1all = (bf16*)alloc(513ull * HB * 2);   // slot s = h1 after s steps
    bf16*  h2a   = (bf16*)alloc((size_t)HB * 2);
    bf16*  h2b   = (bf16*)alloc((size_t)HB * 2);
    bf16*  hd1b  = (bf16*)alloc((size_t)HB * 2);
    bf16*  hd2b  = (bf16*)alloc((size_t)HB * 2);
    float* hf1   = (float*)alloc(2ull * HB * 4);    // f32 ping-pong, layer 1
    float* hf2   = (float*)alloc(2ull * HB * 4);    // f32 ping-pong, layer 2
    float* hd1f  = (float*)alloc((size_t)HB * 4);
    float* hd2f  = (float*)alloc((size_t)HB * 4);
    unsigned* cnt1 = (unsigned*)alloc(1024);
    unsigned* cnt2 = (unsigned*)alloc(1024);

    constexpr int S1 = 98304 + 12288 + 16384;   // pass1 / dec1 LDS bytes
    constexpr int S2 = 98304 + 16384;           // pass2 / dec2 LDS bytes
    (void)hipFuncSetAttribute((const void*)gru_pass<128, false, true>,
                              hipFuncAttributeMaxDynamicSharedMemorySize, S1);
    (void)hipFuncSetAttribute((const void*)gru_pass<128, false, false>,
                              hipFuncAttributeMaxDynamicSharedMemorySize, S1);
    (void)hipFuncSetAttribute((const void*)gru_pass<1024, true, false>,
                              hipFuncAttributeMaxDynamicSharedMemorySize, S2);

    // prep
    cvt_x_kernel<<<(T_DIM * B_DIM * I_PAD) / 256, 256, 0, stream>>>(x, x_bf);
    auto cvt = [&](const float* in, bf16* out, int kin, int kp) {
        long total = 3072L * kp;
        cvt_pad<<<(int)((total + 255) / 256), 256, 0, stream>>>(in, out, kin, kp, total);
    };
    cvt(e_Wih0, wih0e, 118, 128);
    cvt(e_Whh0, whh0e, 1024, 1024);
    cvt(e_Wih1, wih1e, 1024, 1024);
    cvt(e_Whh1, whh1e, 1024, 1024);
    cvt(d_Wih0, wih0d, 118, 128);
    cvt(d_Whh0, whh0d, 1024, 1024);
    cvt(d_Wih1, wih1d, 1024, 1024);
    cvt(d_Whh1, whh1d, 1024, 1024);

    hipMemsetAsync(h1all, 0, (size_t)HB * 2, stream);
    hipMemsetAsync(h2a,   0, (size_t)HB * 2, stream);
    hipMemsetAsync(hf1,   0, (size_t)HB * 4, stream);
    hipMemsetAsync(hf2,   0, (size_t)HB * 4, stream);
    hipMemsetAsync(cnt1,  0, 1024, stream);
    hipMemsetAsync(cnt2,  0, 1024, stream);

    // encoder layer 1 (SEQ: h1 slots 0..512)
    gru_pass<128, false, true><<<256, 256, S1, stream>>>(
        x_bf, (long)B_DIM * I_PAD, wih0e, whh0e, e_bih0, e_bhh0,
        h1all, h1all + HB, hf1, hf1 + HB, T_DIM, cnt1);

    // encoder layer 2 (PP; input = h1[t] = slot t+1)
    gru_pass<1024, true, false><<<256, 256, S2, stream>>>(
        h1all + HB, (long)HB, wih1e, whh1e, e_bih1, e_bhh1,
        h2a, h2b, hf2, hf2 + HB, T_DIM, cnt2);
    // final h2: bf16 in h2a, f32 in hf2[0]

    // decoder cell 1: x = x[:,511,:], h = h1[511] (slot 512 / hf1[0])
    gru_pass<128, false, false><<<256, 256, S1, stream>>>(
        x_bf + 511L * B_DIM * I_PAD, 0, wih0d, whh0d, d_bih0, d_bhh0,
        h1all + 512L * HB, hd1b, hf1, hd1f, 1, nullptr);

    // decoder cell 2: x = hd1 (bf16), h = h2 (h2a / hf2[0])
    gru_pass<1024, true, false><<<256, 256, S2, stream>>>(
        hd1b, 0, wih1d, whh1d, d_bih1, d_bhh1,
        h2a, hd2b, hf2, hd2f, 1, nullptr);

    head_kernel<<<1, 1024, 0, stream>>>(hd2f, fc_W, fc_b, out_W, out_b,
                                        (float*)d_out);
}